// Round 8
// baseline (284.517 us; speedup 1.0000x reference)
//
#include <hip/hip_runtime.h>

// SelfAttentionHead R8: occupancy round with DMA staging.
//  qkv      : M=32,BK=32 -> 1024 blocks, 32KB LDS dbuf, 4 blocks/CU (4 waves/SIMD).
//  attn_part: split-s flash chunks (16 tiles x 32 cols), single-wave blocks,
//             9.4KB LDS -> 16 blocks/CU (4 waves/SIMD), DMA K/V staging,
//             no barriers, partials to ws.
//  attn_red : exact flash merge of <=4 partials (R4-verified math).
// Fragment maps (verified R2-R7): A[m=l15][k=Q*8+j] == B[k=Q*8+j][n=l15];
// C/D: col=l15, row=Q*4+reg. Operand swap == transposed product.
// XOR-swizzled LDS (DMA forbids padding): 128B rows: slot=g^(r&7);
// 64B rows: slot=g^((r>>1)&3). Both give 2-way bank aliasing (free).

typedef __bf16 bf16x8 __attribute__((ext_vector_type(8)));
typedef __bf16 bf16x4 __attribute__((ext_vector_type(4)));
typedef float f32x4 __attribute__((ext_vector_type(4)));

constexpr int kE = 1024;
constexpr int kH = 64;
constexpr int kT = 2048;
constexpr int kB = 16;
constexpr int kM = kB * kT;
constexpr float kQScale = 0.125f * 1.44269504088896340736f;  // H^-0.5 * log2(e)

#define MFMA16(a, b, c) __builtin_amdgcn_mfma_f32_16x16x32_bf16((a), (b), (c), 0, 0, 0)

__device__ __forceinline__ void gl_lds16(const void* g, void* l) {
    __builtin_amdgcn_global_load_lds(
        (const __attribute__((address_space(1))) void*)g,
        (__attribute__((address_space(3))) void*)l, 16, 0, 0);
}

// ---------------------------------------------------------------- prep_w
__global__ __launch_bounds__(256)
void prep_w(const float* __restrict__ Wq, const float* __restrict__ Wk,
            const float* __restrict__ Wv, __bf16* __restrict__ WbT)
{
    __shared__ float tl[64][65];
    const int mat = blockIdx.x >> 4;
    const int k0 = (blockIdx.x & 15) * 64;
    const float* src = (mat == 0) ? Wq : (mat == 1) ? Wk : Wv;

    const int t = threadIdx.x;
    const int kr = t >> 2;
    const int cg = (t & 3) * 16;
    #pragma unroll
    for (int i = 0; i < 4; ++i) {
        float4 v = *(const float4*)&src[(size_t)(k0 + kr) * kH + cg + 4 * i];
        tl[cg + 4 * i + 0][kr] = v.x;
        tl[cg + 4 * i + 1][kr] = v.y;
        tl[cg + 4 * i + 2][kr] = v.z;
        tl[cg + 4 * i + 3][kr] = v.w;
    }
    __syncthreads();
    const int nl = t >> 2;
    const int kg = (t & 3) * 16;
    bf16x8 o0, o1;
    #pragma unroll
    for (int j = 0; j < 8; ++j) {
        o0[j] = (__bf16)tl[nl][kg + j];
        o1[j] = (__bf16)tl[nl][kg + 8 + j];
    }
    *(bf16x8*)&WbT[(size_t)(mat * 64 + nl) * kE + k0 + kg] = o0;
    *(bf16x8*)&WbT[(size_t)(mat * 64 + nl) * kE + k0 + kg + 8] = o1;
}

// ---------------------------------------------------------------- qkv
// 1024 blocks, 256 threads (4 waves). Block: 32 rows x 192 cols, BK=32.
// Wave w: m-tiles 0..1, n-tiles 3w..3w+2. LDS 32KB dbuf -> 4 blocks/CU.
// A-LDS: 32 rows x 128B (f32), slot = g ^ (r&7), g = 16B group.
// B-LDS: 192 rows x 64B (bf16), slot = g ^ ((n>>1)&3).
__global__ __launch_bounds__(256, 4)
void qkv(const float* __restrict__ x, const __bf16* __restrict__ WbT,
         __bf16* __restrict__ qo, __bf16* __restrict__ ko, __bf16* __restrict__ vT)
{
    __shared__ __align__(16) char Ab[2][4096];
    __shared__ __align__(16) char Bb[2][12288];

    const int t = threadIdx.x;
    const int lane = t & 63;
    const int w = t >> 6;
    const int l15 = lane & 15;
    const int Q = lane >> 4;
    const int row0 = blockIdx.x * 32;

    f32x4 acc[2][3];
    #pragma unroll
    for (int mt = 0; mt < 2; ++mt)
        #pragma unroll
        for (int nt = 0; nt < 3; ++nt) acc[mt][nt] = (f32x4){0.f, 0.f, 0.f, 0.f};

    // DMA: A 4 instrs (1/wave, 8 rows each), B 12 instrs (3/wave, 16 rows each)
    const int gA = (lane & 7) ^ (lane >> 3);
    const int gB = (lane & 3) ^ ((lane >> 3) & 3);
    auto stage = [&](int p, int k0) {
        gl_lds16(&x[(size_t)(row0 + 8 * w + (lane >> 3)) * kE + k0 + gA * 4],
                 &Ab[p][w * 1024]);
        #pragma unroll
        for (int jj = 0; jj < 3; ++jj) {
            const int j = w * 3 + jj;
            gl_lds16(&WbT[(size_t)(16 * j + (lane >> 2)) * kE + k0 + gB * 8],
                     &Bb[p][j * 1024]);
        }
    };

    stage(0, 0);
    __syncthreads();

    for (int c = 0; c < 32; ++c) {
        const int p = c & 1;
        if (c < 31) stage(1 - p, (c + 1) * 32);

        bf16x8 af[2];
        #pragma unroll
        for (int mt = 0; mt < 2; ++mt) {
            const int row = mt * 16 + l15;
            float4 u0 = *(const float4*)&Ab[p][row * 128 + (((2 * Q + 0) ^ (l15 & 7)) * 16)];
            float4 u1 = *(const float4*)&Ab[p][row * 128 + (((2 * Q + 1) ^ (l15 & 7)) * 16)];
            bf16x8 a;
            a[0] = (__bf16)u0.x; a[1] = (__bf16)u0.y;
            a[2] = (__bf16)u0.z; a[3] = (__bf16)u0.w;
            a[4] = (__bf16)u1.x; a[5] = (__bf16)u1.y;
            a[6] = (__bf16)u1.z; a[7] = (__bf16)u1.w;
            af[mt] = a;
        }
        #pragma unroll
        for (int nt = 0; nt < 3; ++nt) {
            const int n = w * 48 + nt * 16 + l15;
            bf16x8 b = *(const bf16x8*)&Bb[p][n * 64 + (((Q ^ ((l15 >> 1) & 3)) * 16))];
            #pragma unroll
            for (int mt = 0; mt < 2; ++mt)
                acc[mt][nt] = MFMA16(af[mt], b, acc[mt][nt]);
        }
        __syncthreads();
    }

    const int batch = row0 >> 11;
    const int tr0 = row0 & 2047;
    #pragma unroll
    for (int nt = 0; nt < 3; ++nt) {
        const int col0 = w * 48 + nt * 16;
        const int mat = col0 >> 6;
        const int c_ = (col0 & 63) + l15;
        if (mat == 2) {
            #pragma unroll
            for (int mt = 0; mt < 2; ++mt) {
                const int trow = tr0 + mt * 16 + Q * 4;
                bf16x4 pk;
                #pragma unroll
                for (int r = 0; r < 4; ++r) pk[r] = (__bf16)acc[mt][nt][r];
                *(bf16x4*)&vT[((size_t)batch * kH + c_) * kT + trow] = pk;
            }
        } else {
            __bf16* dst = (mat == 0) ? qo : ko;
            const float sc_ = (mat == 0) ? kQScale : 1.0f;
            #pragma unroll
            for (int mt = 0; mt < 2; ++mt)
                #pragma unroll
                for (int r = 0; r < 4; ++r) {
                    const size_t row = row0 + mt * 16 + Q * 4 + r;
                    dst[row * kH + c_] = (__bf16)(acc[mt][nt][r] * sc_);
                }
        }
    }
}

// ---------------------------------------------------------------- attn_part
// 8192 single-wave blocks: (batch, q16 desc, chunk of 16 32-col tiles).
// Lane l15 owns q-row q16*16+l15. LDS 9.4KB -> 16 blocks/CU (4 waves/SIMD).
// K-LDS: 32 s-rows x 128B, slot=g^(s&7). V-LDS: 64 h-rows x 64B, slot=g^((h>>1)&3).
__global__ __launch_bounds__(64, 4)
void attn_part(const __bf16* __restrict__ qm, const __bf16* __restrict__ km,
               const __bf16* __restrict__ vT, float* __restrict__ pO,
               float* __restrict__ pml)
{
    __shared__ __align__(16) char Kb[4096];
    __shared__ __align__(16) char Vb[4096];
    __shared__ __align__(16) __bf16 Ps[16][40];

    const int lane = threadIdx.x;
    const int l15 = lane & 15;
    const int Q = lane >> 4;

    const int bid = blockIdx.x;
    const int c = bid & 3;
    const int q16 = 127 - ((bid >> 2) & 127);       // long strips first
    const int batch = bid >> 9;
    const int n32 = (q16 + 2) >> 1;                  // total 32-col tiles
    const int nch = (n32 + 15) >> 4;
    if (c >= nch) return;
    const int j0 = c * 16;
    const int j1 = min(j0 + 16, n32);
    const int qrow = q16 * 16 + l15;

    const __bf16* qb = qm + (size_t)batch * kT * kH;
    const __bf16* kb = km + (size_t)batch * kT * kH;
    const __bf16* vb = vT + (size_t)batch * kH * kT;

    const int gK = (lane & 7) ^ (lane >> 3);
    const int gV = (lane & 3) ^ ((lane >> 3) & 3);
    auto stage = [&](int j) {
        const int s0 = j * 32;
        #pragma unroll
        for (int i = 0; i < 4; ++i) {
            gl_lds16(&kb[(size_t)(s0 + 8 * i + (lane >> 3)) * kH + gK * 8],
                     &Kb[i * 1024]);
            gl_lds16(&vb[(size_t)(16 * i + (lane >> 2)) * kT + s0 + gV * 8],
                     &Vb[i * 1024]);
        }
    };

    bf16x8 aq[2];
    aq[0] = *(const bf16x8*)&qb[(size_t)qrow * kH + Q * 8];
    aq[1] = *(const bf16x8*)&qb[(size_t)qrow * kH + 32 + Q * 8];

    f32x4 O[4];
    #pragma unroll
    for (int i = 0; i < 4; ++i) O[i] = (f32x4){0.f, 0.f, 0.f, 0.f};
    float m_ = -3.0e38f, l_ = 0.f;

    stage(j0);
    asm volatile("s_waitcnt vmcnt(0)" ::: "memory");

    for (int j = j0; j < j1; ++j) {
        // 1. fragments LDS -> regs
        bf16x8 kf[2][2], vf[4];
        #pragma unroll
        for (int ks = 0; ks < 2; ++ks)
            #pragma unroll
            for (int nt = 0; nt < 2; ++nt)
                kf[ks][nt] = *(const bf16x8*)
                    &Kb[(nt * 16 + l15) * 128 + (((ks * 4 + Q) ^ (l15 & 7)) * 16)];
        #pragma unroll
        for (int ht = 0; ht < 4; ++ht)
            vf[ht] = *(const bf16x8*)
                &Vb[(ht * 16 + l15) * 64 + (((Q ^ ((l15 >> 1) & 3)) * 16))];
        asm volatile("s_waitcnt lgkmcnt(0)" ::: "memory");

        // 2. DMA prefetch next tile into same buffers
        if (j + 1 < j1) stage(j + 1);

        // 3. S^T = K * Q^T  (32 s-rows x 16 q-cols)
        f32x4 sacc[2];
        sacc[0] = (f32x4){0.f, 0.f, 0.f, 0.f};
        sacc[1] = (f32x4){0.f, 0.f, 0.f, 0.f};
        #pragma unroll
        for (int ks = 0; ks < 2; ++ks)
            #pragma unroll
            for (int nt = 0; nt < 2; ++nt)
                sacc[nt] = MFMA16(kf[ks][nt], aq[ks], sacc[nt]);

        if (j == n32 - 1) {   // only the diagonal tile masks
            const int s0 = j * 32;
            #pragma unroll
            for (int nt = 0; nt < 2; ++nt)
                #pragma unroll
                for (int r = 0; r < 4; ++r)
                    if (s0 + nt * 16 + Q * 4 + r > qrow) sacc[nt][r] = -3.0e38f;
        }

        // online softmax: 8-reg reduce + 2 shuffles
        float mx = sacc[0][0];
        #pragma unroll
        for (int nt = 0; nt < 2; ++nt)
            #pragma unroll
            for (int r = 0; r < 4; ++r) mx = fmaxf(mx, sacc[nt][r]);
        mx = fmaxf(mx, __shfl_xor(mx, 16));
        mx = fmaxf(mx, __shfl_xor(mx, 32));
        const float mnew = fmaxf(m_, mx);
        const float alpha = __builtin_amdgcn_exp2f(m_ - mnew);
        float rs = 0.f;
        #pragma unroll
        for (int nt = 0; nt < 2; ++nt)
            #pragma unroll
            for (int r = 0; r < 4; ++r) {
                const float pv = __builtin_amdgcn_exp2f(sacc[nt][r] - mnew);
                sacc[nt][r] = pv;
                rs += pv;
            }
        rs += __shfl_xor(rs, 16);
        rs += __shfl_xor(rs, 32);
        l_ = l_ * alpha + rs;
        m_ = mnew;
        #pragma unroll
        for (int ht = 0; ht < 4; ++ht) O[ht] *= alpha;

        // P^T round-trip (wave-private strip)
        #pragma unroll
        for (int nt = 0; nt < 2; ++nt) {
            bf16x4 pk;
            #pragma unroll
            for (int r = 0; r < 4; ++r) pk[r] = (__bf16)sacc[nt][r];
            *(bf16x4*)&Ps[l15][nt * 16 + Q * 4] = pk;
        }
        bf16x8 pb = *(const bf16x8*)&Ps[l15][Q * 8];

        // O^T += V^T * P^T
        #pragma unroll
        for (int ht = 0; ht < 4; ++ht)
            O[ht] = MFMA16(vf[ht], pb, O[ht]);

        // 4. prefetch landed before next iter reads LDS
        asm volatile("s_waitcnt vmcnt(0)" ::: "memory");
    }

    const int task = ((batch * 128 + q16) << 2) + c;
    float* po = pO + ((size_t)task * 64 + lane) * 16;
    #pragma unroll
    for (int ht = 0; ht < 4; ++ht) {
        float4 o4;
        o4.x = O[ht][0]; o4.y = O[ht][1]; o4.z = O[ht][2]; o4.w = O[ht][3];
        *(float4*)&po[ht * 4] = o4;
    }
    if (Q == 0) {
        pml[task * 32 + l15 * 2] = m_;
        pml[task * 32 + l15 * 2 + 1] = l_;
    }
}

// ---------------------------------------------------------------- attn_red
// 2048 blocks x 64 thr: one per (batch, q16). Exact flash merge of <=4 partials.
__global__ __launch_bounds__(64)
void attn_red(const float* __restrict__ pO, const float* __restrict__ pml,
              float* __restrict__ out)
{
    const int lane = threadIdx.x;
    const int l15 = lane & 15;
    const int Q = lane >> 4;
    const int q16 = blockIdx.x & 127;
    const int batch = blockIdx.x >> 7;
    const int n32 = (q16 + 2) >> 1;
    const int nch = (n32 + 15) >> 4;
    const int base = (batch * 128 + q16) << 2;

    float M = -3.0e38f;
    for (int c = 0; c < nch; ++c)
        M = fmaxf(M, pml[(base + c) * 32 + l15 * 2]);

    float L = 0.f;
    f32x4 O[4];
    #pragma unroll
    for (int i = 0; i < 4; ++i) O[i] = (f32x4){0.f, 0.f, 0.f, 0.f};

    for (int c = 0; c < nch; ++c) {
        const float mc = pml[(base + c) * 32 + l15 * 2];
        const float lc = pml[(base + c) * 32 + l15 * 2 + 1];
        const float sc = __builtin_amdgcn_exp2f(mc - M);
        L += sc * lc;
        const float* po = pO + ((size_t)(base + c) * 64 + lane) * 16;
        #pragma unroll
        for (int ht = 0; ht < 4; ++ht) {
            float4 o4 = *(const float4*)&po[ht * 4];
            O[ht][0] += sc * o4.x; O[ht][1] += sc * o4.y;
            O[ht][2] += sc * o4.z; O[ht][3] += sc * o4.w;
        }
    }

    const float inv = 1.0f / L;
    float* orow = out + ((size_t)batch * kT + q16 * 16 + l15) * kH;
    #pragma unroll
    for (int ht = 0; ht < 4; ++ht) {
        float4 o4;
        o4.x = O[ht][0] * inv; o4.y = O[ht][1] * inv;
        o4.z = O[ht][2] * inv; o4.w = O[ht][3] * inv;
        *(float4*)&orow[ht * 16 + Q * 4] = o4;
    }
}

extern "C" void kernel_launch(void* const* d_in, const int* in_sizes, int n_in,
                              void* d_out, int out_size, void* d_ws, size_t ws_size,
                              hipStream_t stream)
{
    (void)in_sizes; (void)n_in; (void)out_size; (void)ws_size;
    const float* x  = (const float*)d_in[0];
    const float* Wk = (const float*)d_in[1];
    const float* Wq = (const float*)d_in[2];
    const float* Wv = (const float*)d_in[3];

    __bf16* WbT  = (__bf16*)d_ws;                      // 384 KiB
    __bf16* qb   = WbT + (size_t)192 * kE;             // 4 MiB each
    __bf16* kbuf = qb + (size_t)kM * kH;
    __bf16* vT   = kbuf + (size_t)kM * kH;
    float*  pO   = (float*)(vT + (size_t)kM * kH);     // 8192*64*16 f32 = 32 MiB
    float*  pml  = pO + (size_t)8192 * 64 * 16;        // 1 MiB

    prep_w<<<48, 256, 0, stream>>>(Wq, Wk, Wv, WbT);
    qkv<<<kM / 32, 256, 0, stream>>>(x, WbT, qb, kbuf, vT);
    attn_part<<<16 * 128 * 4, 64, 0, stream>>>(qb, kbuf, vT, pO, pml);
    attn_red<<<16 * 128, 64, 0, stream>>>(pO, pml, (float*)d_out);
}